// Round 6
// baseline (112.191 us; speedup 1.0000x reference)
//
#include <hip/hip_runtime.h>
#include <math.h>

#define PROJ 8192
#define NB   16
#define NC   512
#define HW   196    // 14*14
#define KP   224    // K zero-padded to 7 chunks of 32
#define NKC  7

typedef __attribute__((ext_vector_type(8))) short bf16x8;   // MFMA A/B frag
typedef __attribute__((ext_vector_type(4))) float f32x4;    // MFMA C/D frag

__device__ __forceinline__ unsigned bf16_rne(float f) {
    unsigned u = __builtin_bit_cast(unsigned, f);
    return (u + 0x7fffu + ((u >> 16) & 1u)) >> 16;
}

// ---------------------------------------------------------------------------
// Kernel 0: pre-convert x -> sign-folded split-bf16, zero-padded K=224.
// X1h/X1l = s1-folded (A operand), X2h/X2l = s2-folded (B operand).
// Layout [b][c][kp] shorts (row stride 448 B, 16B-aligned). Each element
// converted ONCE, streaming -- removes the 3x-redundant convert that made the
// round-5 Gram loop a serial load->480-VALU->MFMA chain (VALUBusy 20%).
// Arithmetic identical to baseline: hi=rne(s*x), lo=rne(s*x-hi); pad = s*0.
// grid = 896 x 256 (16*512*28 threads, 8 k-elems each).
// ---------------------------------------------------------------------------
__global__ __launch_bounds__(256)
void cbp_convert(const float* __restrict__ x,
                 const float* __restrict__ s1,
                 const float* __restrict__ s2,
                 short* __restrict__ X1h, short* __restrict__ X1l,
                 short* __restrict__ X2h, short* __restrict__ X2l) {
    const int v   = blockIdx.x * 256 + threadIdx.x;
    const int b   = v / (NC * 28);
    const int rem = v - b * (NC * 28);
    const int c   = rem / 28;
    const int g   = rem - c * 28;
    const int kk  = g * 8;

    const float* xs = x + ((size_t)b * NC + c) * HW;
    float4 f0 = {0.f,0.f,0.f,0.f}, f1 = {0.f,0.f,0.f,0.f};
    if (g < 24) {                       // rows are 784 B -> float4-aligned
        f0 = *(const float4*)(xs + kk);
        f1 = *(const float4*)(xs + kk + 4);
    } else if (g == 24) {
        f0 = *(const float4*)(xs + kk); // k=192..195; 196..199 stay zero
    }                                   // g>24: all pad
    const float w1 = s1[c], w2 = s2[c];
    const float f[8] = {f0.x, f0.y, f0.z, f0.w, f1.x, f1.y, f1.z, f1.w};
    bf16x8 h1v, l1v, h2v, l2v;
#pragma unroll
    for (int e = 0; e < 8; ++e) {
        const float a1 = f[e] * w1;
        const unsigned u1 = bf16_rne(a1);
        h1v[e] = (short)u1;
        l1v[e] = (short)bf16_rne(a1 - __builtin_bit_cast(float, u1 << 16));
        const float a2 = f[e] * w2;
        const unsigned u2 = bf16_rne(a2);
        h2v[e] = (short)u2;
        l2v[e] = (short)bf16_rne(a2 - __builtin_bit_cast(float, u2 << 16));
    }
    const size_t off = ((size_t)b * NC + c) * KP + kk;
    *(bf16x8*)(X1h + off) = h1v;
    *(bf16x8*)(X1l + off) = l1v;
    *(bf16x8*)(X2h + off) = h2v;
    *(bf16x8*)(X2l + off) = l2v;
}

// ---------------------------------------------------------------------------
// Kernel 1: barrier-free Gram, pure load->MFMA inner loop (no convert VALU,
// no predication -- pad is pre-zeroed). grid = 256 x 512 (8 waves).
// Explicit 2-deep double buffer, fully unrolled (static indices); 12 bf16x8
// frags/parity = 96 VGPR now fits (no convert temps competing).
// Only 2 barriers total (before scatter, before dump).
//   block -> (batch,tile): b = 2*(blk&7) + (blk>>7), tile = (blk>>3)&15
// ---------------------------------------------------------------------------
__global__ __launch_bounds__(512, 2)
void cbp_gram(const short* __restrict__ X1h, const short* __restrict__ X1l,
              const short* __restrict__ X2h, const short* __restrict__ X2l,
              const int*   __restrict__ h1,  const int*   __restrict__ h2,
              float* __restrict__ ws) {
    __shared__ float sk[PROJ];         // 32 KB private sketch
    __shared__ int   lh1[128], lh2[128];

    const int tid = threadIdx.x;
    const int blk = blockIdx.x;
    const int b    = 2 * (blk & 7) + (blk >> 7);   // XCD-pinned batch
    const int tile = (blk >> 3) & 15;
    const int c1base = (tile >> 2) * 128;
    const int c2base = (tile & 3) * 128;

    const int lane = tid & 63;
    const int wave = tid >> 6;         // 0..7
    const int quad = lane >> 4;        // k-slot: k = kc*32 + quad*8 .. +7
    const int l15  = lane & 15;
    const int wr   = (wave >> 1) * 32; // wave's 32x64 sub-tile
    const int wc   = (wave & 1) * 64;

    for (int i = tid; i < PROJ; i += 512) sk[i] = 0.f;
    if (tid < 128) { lh1[tid] = h1[c1base + tid]; lh2[tid] = h2[c2base + tid]; }

    // Per-lane fragment row pointers (hoisted; signs already folded).
    const short* pAh[2]; const short* pAl[2];
#pragma unroll
    for (int i = 0; i < 2; ++i) {
        const size_t r = (size_t)(b * NC + c1base + wr + i * 16 + l15) * KP;
        pAh[i] = X1h + r;  pAl[i] = X1l + r;
    }
    const short* pBh[4]; const short* pBl[4];
#pragma unroll
    for (int j = 0; j < 4; ++j) {
        const size_t r = (size_t)(b * NC + c2base + wc + j * 16 + l15) * KP;
        pBh[j] = X2h + r;  pBl[j] = X2l + r;
    }

    f32x4 acc[2][4];
#pragma unroll
    for (int i = 0; i < 2; ++i)
#pragma unroll
        for (int j = 0; j < 4; ++j) acc[i][j] = (f32x4){0.f, 0.f, 0.f, 0.f};

    bf16x8 buf[2][12];   // [parity][Ah0,Al0,Ah1,Al1,Bh0,Bl0,..,Bh3,Bl3]

#define LOADC(par, kc) do {                                                   \
    const int kk_ = (kc) * 32 + quad * 8;                                     \
    _Pragma("unroll") for (int i_ = 0; i_ < 2; ++i_) {                        \
        buf[par][2*i_]   = *(const bf16x8*)(pAh[i_] + kk_);                   \
        buf[par][2*i_+1] = *(const bf16x8*)(pAl[i_] + kk_); }                 \
    _Pragma("unroll") for (int j_ = 0; j_ < 4; ++j_) {                        \
        buf[par][4+2*j_]   = *(const bf16x8*)(pBh[j_] + kk_);                 \
        buf[par][4+2*j_+1] = *(const bf16x8*)(pBl[j_] + kk_); }               \
} while (0)

    LOADC(0, 0);
#pragma unroll
    for (int kc = 0; kc < NKC; ++kc) {
        const int cur = kc & 1;
        if (kc + 1 < NKC) LOADC(cur ^ 1, kc + 1);   // prefetch next chunk

#pragma unroll
        for (int i = 0; i < 2; ++i)
#pragma unroll
            for (int j = 0; j < 4; ++j) {
                const bf16x8 ah = buf[cur][2*i],     al = buf[cur][2*i+1];
                const bf16x8 bh = buf[cur][4+2*j],   bl = buf[cur][4+2*j+1];
                acc[i][j] = __builtin_amdgcn_mfma_f32_16x16x32_bf16(ah, bh, acc[i][j], 0, 0, 0);
                acc[i][j] = __builtin_amdgcn_mfma_f32_16x16x32_bf16(ah, bl, acc[i][j], 0, 0, 0);
                acc[i][j] = __builtin_amdgcn_mfma_f32_16x16x32_bf16(al, bh, acc[i][j], 0, 0, 0);
            }
    }
#undef LOADC

    __syncthreads();   // sk zeroed + lh1/lh2 ready (first barrier in kernel)

    // Scatter (signs pre-folded): C/D layout col=lane&15, row=quad*4+reg.
#pragma unroll
    for (int i = 0; i < 2; ++i) {
        const int lr0 = wr + i * 16 + quad * 4;
#pragma unroll
        for (int j = 0; j < 4; ++j) {
            const int h2v = lh2[wc + j * 16 + l15];
#pragma unroll
            for (int rg = 0; rg < 4; ++rg) {
                const int bin = (lh1[lr0 + rg] + h2v) & (PROJ - 1);
                atomicAdd(&sk[bin], acc[i][j][rg]);   // ds_add_f32
            }
        }
    }
    __syncthreads();

    // Dump private sketch to ws.
    float4* dst = (float4*)(ws + (size_t)blk * PROJ);
    const float4* src = (const float4*)sk;
    for (int i = tid; i < PROJ / 4; i += 512) dst[i] = src[i];
}

__device__ __forceinline__ float ssqrt(float s) {
    const float m = sqrtf(fabsf(s) + 1e-8f);
    return (s > 0.f) ? m : (s < 0.f ? -m : 0.f);   // sign(0)=0
}

// ---------------------------------------------------------------------------
// Kernel 2: per-batch finalize. grid = 16 x 512. Sum 16 partials/bin (same
// t-order as verified reduce), signed sqrt, ssq shuffle-reduce, normalize,
// single y write.
// ---------------------------------------------------------------------------
__global__ __launch_bounds__(512)
void cbp_finalize(const float* __restrict__ ws, float* __restrict__ y) {
    __shared__ float red[8];
    const int b   = blockIdx.x;
    const int tid = threadIdx.x;
    const int pbase = ((b & 1) << 7) | (b >> 1);   // physical partial base

    float4 ov[4];
    float ssq = 0.f;
#pragma unroll
    for (int g = 0; g < 4; ++g) {
        const int f4 = tid + 512 * g;              // float4 index in [0,2048)
        float4 s = {0.f, 0.f, 0.f, 0.f};
#pragma unroll
        for (int t = 0; t < 16; ++t) {
            const float4 v =
                ((const float4*)(ws + (size_t)(pbase | (t << 3)) * PROJ))[f4];
            s.x += v.x; s.y += v.y; s.z += v.z; s.w += v.w;
        }
        float4 o;
        o.x = ssqrt(s.x); o.y = ssqrt(s.y); o.z = ssqrt(s.z); o.w = ssqrt(s.w);
        ov[g] = o;
        ssq += o.x * o.x + o.y * o.y + o.z * o.z + o.w * o.w;
    }

    float v = ssq;
#pragma unroll
    for (int off = 32; off >= 1; off >>= 1) v += __shfl_xor(v, off, 64);
    if ((tid & 63) == 0) red[tid >> 6] = v;
    __syncthreads();
    float tot = 0.f;
#pragma unroll
    for (int w = 0; w < 8; ++w) tot += red[w];
    const float inv = 1.0f / fmaxf(sqrtf(tot), 1e-12f);

    float4* yp = (float4*)(y + (size_t)b * PROJ);
#pragma unroll
    for (int g = 0; g < 4; ++g) {
        float4 o = ov[g];
        o.x *= inv; o.y *= inv; o.z *= inv; o.w *= inv;
        yp[tid + 512 * g] = o;
    }
}

// ---------------------------------------------------------------------------
extern "C" void kernel_launch(void* const* d_in, const int* in_sizes, int n_in,
                              void* d_out, int out_size, void* d_ws, size_t ws_size,
                              hipStream_t stream) {
    const float* x  = (const float*)d_in[0];
    const float* s1 = (const float*)d_in[1];
    const float* s2 = (const float*)d_in[2];
    const int*   h1 = (const int*)d_in[3];
    const int*   h2 = (const int*)d_in[4];
    float* y  = (float*)d_out;                     // [16, 8192]
    float* ws = (float*)d_ws;

    // ws map: [0, 8MB) partial sketches; then 4 split-bf16 arrays (3.67 MB ea).
    short* X1h = (short*)(ws + (size_t)256 * PROJ);
    short* X1l = X1h + (size_t)NB * NC * KP;
    short* X2h = X1l + (size_t)NB * NC * KP;
    short* X2l = X2h + (size_t)NB * NC * KP;

    hipLaunchKernelGGL(cbp_convert, dim3(896), dim3(256), 0, stream,
                       x, s1, s2, X1h, X1l, X2h, X2l);
    hipLaunchKernelGGL(cbp_gram, dim3(256), dim3(512), 0, stream,
                       X1h, X1l, X2h, X2l, h1, h2, ws);
    hipLaunchKernelGGL(cbp_finalize, dim3(16), dim3(512), 0, stream, ws, y);
}